// Round 6
// baseline (528.064 us; speedup 1.0000x reference)
//
#include <hip/hip_runtime.h>
#include <stdint.h>

// RBM CD-4, fused single kernel. 512 blocks x 32 rows (16 low rows bt16..bt16+15
// paired with bt16+8192..+15; pair shares one 32-bit hash: lo16/hi16).
// h-pass: C^T[j][b] = W^T X^T, K=4096, 64 chunks staged via global_load_lds into a
//   RING-3 LDS buffer with prefetch depth 2 and COUNTED s_waitcnt vmcnt(2) (r5 used
//   vmcnt(0), which drained the prefetch -> full load latency per chunk).
// x-pass: K=128, barrier-free, direct WX2 loads register-double-buffered.
// RNG: lowbias32 counter hash; sample via fma(h,q,h) < 65536 (no rcp).
// ws: [WTC 1MB][WX2 1MB][S 2 doubles]

#define BB 16384
#define DD 4096
#define HH 128

typedef float f32x4 __attribute__((ext_vector_type(4)));
typedef short s16x8 __attribute__((ext_vector_type(8)));

struct RbmKeys { uint32_t kh[4]; uint32_t kx[4]; };

// host-only: threefry for key derivation
static void tf2x32_host(uint32_t k0, uint32_t k1, uint32_t x0, uint32_t x1,
                        uint32_t& o0, uint32_t& o1) {
  uint32_t ks2 = k0 ^ k1 ^ 0x1BD11BDAu;
  x0 += k0; x1 += k1;
#define TFR(r) { x0 += x1; x1 = (x1 << (r)) | (x1 >> (32 - (r))); x1 ^= x0; }
  TFR(13) TFR(15) TFR(26) TFR(6)
  x0 += k1; x1 += ks2 + 1u;
  TFR(17) TFR(29) TFR(16) TFR(24)
  x0 += ks2; x1 += k0 + 2u;
  TFR(13) TFR(15) TFR(26) TFR(6)
  x0 += k0; x1 += k1 + 3u;
  TFR(17) TFR(29) TFR(16) TFR(24)
  x0 += k1; x1 += ks2 + 4u;
  TFR(13) TFR(15) TFR(26) TFR(6)
  x0 += ks2; x1 += k0 + 5u;
#undef TFR
  o0 = x0; o1 = x1;
}

__device__ __forceinline__ uint32_t mix32(uint32_t x) {   // lowbias32
  x ^= x >> 16; x *= 0x21f0aaadu;
  x ^= x >> 15; x *= 0x735a2d97u;
  x ^= x >> 15;
  return x;
}

// sample: u16 < 65536*sigm(z)  <=>  fma(h, 2^(-z*log2e), h) < 65536
__device__ __forceinline__ bool samp16(uint32_t h16, float z) {
  float q = __builtin_amdgcn_exp2f(-1.442695041f * z);
  float hf = (float)h16;
  return fmaf(hf, q, hf) < 65536.0f;
}
__device__ __forceinline__ float softplusf(float z) {
  float e = __builtin_amdgcn_exp2f(-1.442695041f * fabsf(z));
  return fmaxf(z, 0.0f) + log1pf(e);
}

__device__ __forceinline__ void gload16(const void* g, void* l) {
  __builtin_amdgcn_global_load_lds(
      (const __attribute__((address_space(1))) uint32_t*)(uintptr_t)g,
      (__attribute__((address_space(3))) uint32_t*)(uintptr_t)l, 16, 0, 0);
}

// byte (8 bits) -> 8 packed bf16 {0,1}
__device__ __forceinline__ s16x8 expand8(uint32_t byte) {
  uint32_t n0 = byte & 0xFu, n1 = byte >> 4;
  union { s16x8 v; uint32_t u[4]; } r;
  r.u[0] = ((n0 * 0x40008001u) & 0x00010001u) * 0x3F80u;
  r.u[1] = (((n0 >> 2) * 0x40008001u) & 0x00010001u) * 0x3F80u;
  r.u[2] = ((n1 * 0x40008001u) & 0x00010001u) * 0x3F80u;
  r.u[3] = (((n1 >> 2) * 0x40008001u) & 0x00010001u) * 0x3F80u;
  return r.v;
}

// ---- W fp32 [D][H] -> WTC (h-image: 64-d chunks [128 j][64 d], XOR-swizzled)
//                    -> WX2 (x-image: [dt=d>>4][jg=j>>3][dl=d&15][je=j&7], 16B/lane)
__global__ __launch_bounds__(512) void k_prep(const float* __restrict__ W,
                                              unsigned short* __restrict__ WTC,
                                              unsigned short* __restrict__ WX2) {
  unsigned idx = blockIdx.x * 512u + threadIdx.x;   // over D*H
  uint32_t u = __float_as_uint(W[idx]);
  unsigned short r = (unsigned short)((u + 0x7FFFu + ((u >> 16) & 1u)) >> 16); // RTNE
  unsigned d = idx >> 7, j = idx & 127u;
  unsigned c = d >> 6, dloc = d & 63u;
  WTC[c * 8192u + j * 64u + (dloc ^ ((j & 7u) << 3))] = r;
  WX2[((d >> 4) * 16u + (j >> 3)) * 128u + (d & 15u) * 8u + (j & 7u)] = r;
}

__global__ __launch_bounds__(512, 4) void k_rbm(const float* __restrict__ x,
                                                const unsigned short* __restrict__ WTC,
                                                const unsigned short* __restrict__ WX2,
                                                const float* __restrict__ bx,
                                                const float* __restrict__ bh,
                                                double* __restrict__ S,
                                                RbmKeys K) {
  __shared__ unsigned short wt[3][8192];   // 48 KB ring-3 chunk buffer (h-pass)
  __shared__ uint32_t xbits[32 * 132];     // 16.9 KB: 32 rows x 128 words (+4 pad)
  __shared__ uint32_t hb[32 * 4];          // 512 B
  __shared__ double sred[8];

  const int t = threadIdx.x;
  const int l = t & 63;
  const int w = t >> 6;
  const int rs = l >> 4;
  const int l15 = l & 15;
  const unsigned bt16 = blockIdx.x * 16u;   // rows: lr<16 -> bt16+lr ; lr>=16 -> +8192

  const int wr = w >> 1, wc = w & 1;   // h-pass: j-quarter (32 j), row-half (16 rows)

  // hoist bh into registers (keeps the chunk loop free of compiler global loads,
  // which makes the counted vmcnt waits safe)
  float bhv[2][4];
#pragma unroll
  for (int rg = 0; rg < 2; ++rg)
#pragma unroll
    for (int reg = 0; reg < 4; ++reg)
      bhv[rg][reg] = bh[wr * 32 + rg * 16 + rs * 4 + reg];

  // ---------- P0: load x rows, pack bits, accumulate x.bx ----------
  {
    float vbx = 0.f;
#pragma unroll 1
    for (int q = 0; q < 4; ++q) {
      const int lr = w * 4 + q;
      const unsigned g = bt16 + (unsigned)(lr & 15) + (unsigned)((lr >> 4) << 13);
      const f32x4* xrow = (const f32x4*)(x + (size_t)g * DD);
#pragma unroll
      for (int it = 0; it < 16; ++it) {
        f32x4 v = xrow[it * 64 + l];
        f32x4 bv = *(const f32x4*)(bx + it * 256 + l * 4);
        vbx += v.x * bv.x + v.y * bv.y + v.z * bv.z + v.w * bv.w;
        uint32_t nib = (v.x != 0.f ? 1u : 0u) | (v.y != 0.f ? 2u : 0u) |
                       (v.z != 0.f ? 4u : 0u) | (v.w != 0.f ? 8u : 0u);
        uint32_t word = nib << (4 * (l & 7));
        word |= __shfl_xor(word, 1);
        word |= __shfl_xor(word, 2);
        word |= __shfl_xor(word, 4);
        if ((l & 7) == 0) xbits[lr * 132 + it * 8 + (l >> 3)] = word;
      }
    }
#pragma unroll
    for (int off = 32; off; off >>= 1) vbx += __shfl_xor(vbx, off);
    if (l == 0) sred[w] = (double)vbx;
    __syncthreads();
    if (t == 0) {
      double s = 0.0;
      for (int i = 0; i < 8; ++i) s += sred[i];
      atomicAdd(S + 0, s);
    }
  }

#pragma unroll 1
  for (int step = 0; step < 5; ++step) {
    // ================= h-pass: K=4096 over 64 WTC chunks, ring-3, depth-2 =================
    f32x4 acc[2];
    acc[0] = (f32x4){0.f, 0.f, 0.f, 0.f};
    acc[1] = (f32x4){0.f, 0.f, 0.f, 0.f};

    // drain everything (P0 loads / atomics / x-pass loads) so counted waits are exact
    asm volatile("s_waitcnt vmcnt(0)" ::: "memory");
    {
      const char* src = (const char*)WTC + (t << 4);
      char* dst = (char*)&wt[0][0] + (t << 4);
      gload16(src, dst);                       // chunk 0 -> slot 0
      gload16(src + 8192, dst + 8192);
      gload16(src + 16384, dst + 16384);       // chunk 1 -> slot 1
      gload16(src + 24576, dst + 24576);
    }
    int rd = 0, wsl = 2;
#pragma unroll 1
    for (int c = 0; c < 64; ++c) {
      // wait for THIS chunk's loads only; keep c+1's (and soon c+2's) in flight
      if (c < 63) asm volatile("s_waitcnt vmcnt(2)" ::: "memory");
      else        asm volatile("s_waitcnt vmcnt(0)" ::: "memory");
      __syncthreads();
      if (c < 62) {
        const char* src = (const char*)WTC + ((size_t)(c + 2) << 14) + (t << 4);
        char* dst = (char*)&wt[0][0] + (wsl << 14) + (t << 4);
        gload16(src, dst);
        gload16(src + 8192, dst + 8192);
      }
      const int xrow = (wc * 16 + l15) * 132 + c * 2;
      uint32_t w0 = xbits[xrow];
      uint32_t w1 = xbits[xrow + 1];
      const unsigned short* wb = wt[rd];
#pragma unroll
      for (int kk = 0; kk < 2; ++kk) {
        s16x8 bf = expand8(((kk ? w1 : w0) >> (8 * rs)) & 0xffu);
#pragma unroll
        for (int rg = 0; rg < 2; ++rg) {
          const int j = wr * 32 + rg * 16 + l15;
          s16x8 af = *(const s16x8*)&wb[j * 64 + ((kk * 32 + rs * 8) ^ ((l15 & 7) << 3))];
          acc[rg] = __builtin_amdgcn_mfma_f32_16x16x32_bf16(af, bf, acc[rg], 0, 0, 0);
        }
      }
      rd = (rd == 2) ? 0 : rd + 1;
      wsl = (wsl == 2) ? 0 : wsl + 1;
    }

    // ---------- h epilogue: sample h (steps 0-3) / energy (steps 0,4) ----------
    if (step < 4) {
      const uint32_t key = K.kh[step];
      const unsigned glow = bt16 + (unsigned)l15;
      uint32_t mask = 0;
      float loc = 0.f;
#pragma unroll
      for (int rg = 0; rg < 2; ++rg)
#pragma unroll
        for (int reg = 0; reg < 4; ++reg) {
          const int jj = wr * 32 + rg * 16 + rs * 4 + reg;
          float z = acc[rg][reg] + bhv[rg][reg];
          if (step == 0) loc += softplusf(z);
          uint32_t h32 = mix32((glow * 128u + (unsigned)jj) ^ key);
          uint32_t h16 = wc ? (h32 >> 16) : (h32 & 0xffffu);
          mask |= (samp16(h16, z) ? 1u : 0u) << (rg * 16 + rs * 4 + reg);
        }
      mask |= __shfl_xor(mask, 16);
      mask |= __shfl_xor(mask, 32);
      if (rs == 0) hb[(wc * 16 + l15) * 4 + wr] = mask;
      if (step == 0) {
#pragma unroll
        for (int off = 32; off; off >>= 1) loc += __shfl_xor(loc, off);
        if (l == 0) sred[w] = (double)loc;
      }
      __syncthreads();   // hb (and sred) visible
      if (step == 0 && t == 0) {
        double s = 0.0;
        for (int i = 0; i < 8; ++i) s += sred[i];
        atomicAdd(S + 0, s);
      }
    } else {
      float loc = 0.f;
#pragma unroll
      for (int rg = 0; rg < 2; ++rg)
#pragma unroll
        for (int reg = 0; reg < 4; ++reg)
          loc += softplusf(acc[rg][reg] + bhv[rg][reg]);
#pragma unroll
      for (int off = 32; off; off >>= 1) loc += __shfl_xor(loc, off);
      if (l == 0) sred[w] = (double)loc;
      __syncthreads();
      if (t == 0) {
        double s = 0.0;
        for (int i = 0; i < 8; ++i) s += sred[i];
        atomicAdd(S + 1, s);
      }
    }

    // ================= x-pass: K=128, barrier-free, reg-double-buffered WX2 =================
    if (step < 4) {
      const uint32_t key = K.kx[step];
      s16x8 bfr[4][2];   // h B-fragments, hoisted for whole pass
#pragma unroll
      for (int ch = 0; ch < 4; ++ch)
#pragma unroll
        for (int cg = 0; cg < 2; ++cg) {
          uint32_t hw = hb[(cg * 16 + l15) * 4 + ch];
          bfr[ch][cg] = expand8((hw >> (8 * rs)) & 0xffu);
        }
      float vbx1 = 0.f;
      const unsigned mrow = (bt16 + (unsigned)l15) * 4096u;

      s16x8 afA[2][4], afB[2][4];

#define LOAD_AF(DSUB, AF)                                                        \
      {                                                                          \
        _Pragma("unroll")                                                        \
        for (int rg = 0; rg < 2; ++rg) {                                         \
          const unsigned dt = (unsigned)(w * 32 + (DSUB) * 2 + rg);              \
          _Pragma("unroll")                                                      \
          for (int ch = 0; ch < 4; ++ch)                                         \
            AF[rg][ch] = *(const s16x8*)(WX2 + dt * 2048u +                      \
                           (unsigned)(ch * 4 + rs) * 128u + (unsigned)l15 * 8u); \
        }                                                                        \
      }

#define COMPUTE_X(DSUB, AF)                                                      \
      {                                                                          \
        const int dbase = w * 512 + (DSUB) * 32;                                 \
        f32x4 acc2[2][2];                                                        \
        acc2[0][0] = (f32x4){0.f,0.f,0.f,0.f};                                   \
        acc2[0][1] = (f32x4){0.f,0.f,0.f,0.f};                                   \
        acc2[1][0] = (f32x4){0.f,0.f,0.f,0.f};                                   \
        acc2[1][1] = (f32x4){0.f,0.f,0.f,0.f};                                   \
        _Pragma("unroll")                                                        \
        for (int ch = 0; ch < 4; ++ch)                                           \
          _Pragma("unroll")                                                      \
          for (int rg = 0; rg < 2; ++rg)                                         \
            _Pragma("unroll")                                                    \
            for (int cg = 0; cg < 2; ++cg)                                       \
              acc2[rg][cg] = __builtin_amdgcn_mfma_f32_16x16x32_bf16(            \
                  AF[rg][ch], bfr[ch][cg], acc2[rg][cg], 0, 0, 0);               \
        uint32_t ml = 0, mh = 0;                                                 \
        _Pragma("unroll")                                                        \
        for (int rg = 0; rg < 2; ++rg) {                                         \
          f32x4 bx4 = *(const f32x4*)(bx + dbase + rg * 16 + rs * 4);            \
          _Pragma("unroll")                                                      \
          for (int reg = 0; reg < 4; ++reg) {                                    \
            const int pos = rg * 16 + rs * 4 + reg;                              \
            const unsigned d = (unsigned)(dbase + pos);                          \
            uint32_t h32 = mix32((mrow + d) ^ key);                              \
            float zl = acc2[rg][0][reg] + bx4[reg];                              \
            float zh = acc2[rg][1][reg] + bx4[reg];                              \
            bool sl = samp16(h32 & 0xffffu, zl);                                 \
            bool sh = samp16(h32 >> 16, zh);                                     \
            ml |= (sl ? 1u : 0u) << pos;                                         \
            mh |= (sh ? 1u : 0u) << pos;                                         \
            if (step == 3) vbx1 += bx4[reg] * ((sl ? 1.f : 0.f) + (sh ? 1.f : 0.f)); \
          }                                                                      \
        }                                                                        \
        unsigned long long mm = (unsigned long long)ml |                         \
                                ((unsigned long long)mh << 32);                  \
        mm |= __shfl_xor(mm, 16);                                                \
        mm |= __shfl_xor(mm, 32);                                                \
        if (rs == 0) {                                                           \
          xbits[l15 * 132 + w * 16 + (DSUB)] = (uint32_t)mm;                     \
          xbits[(16 + l15) * 132 + w * 16 + (DSUB)] = (uint32_t)(mm >> 32);      \
        }                                                                        \
      }

      LOAD_AF(0, afA)
#pragma unroll 1
      for (int ds2 = 0; ds2 < 8; ++ds2) {
        const int d0 = ds2 * 2;
        LOAD_AF(d0 + 1, afB)         // prefetch odd dsub under even compute
        COMPUTE_X(d0, afA)
        if (ds2 < 7) LOAD_AF(d0 + 2, afA)   // prefetch next even under odd compute
        COMPUTE_X(d0 + 1, afB)
      }
#undef LOAD_AF
#undef COMPUTE_X

      if (step == 3) {
#pragma unroll
        for (int off = 32; off; off >>= 1) vbx1 += __shfl_xor(vbx1, off);
        if (l == 0) sred[w] = (double)vbx1;
        __syncthreads();
        if (t == 0) {
          double s = 0.0;
          for (int i = 0; i < 8; ++i) s += sred[i];
          atomicAdd(S + 1, s);
        }
      }
      // no trailing barrier needed: next h-pass's iter-0 barrier orders xbits
    }
  }
}

__global__ void k_final(const double* __restrict__ S, float* __restrict__ out) {
  if (threadIdx.x == 0 && blockIdx.x == 0)
    out[0] = (float)((S[1] - S[0]) / (double)BB);   // mean F(x) - mean F(x_rec)
}

extern "C" void kernel_launch(void* const* d_in, const int* in_sizes, int n_in,
                              void* d_out, int out_size, void* d_ws, size_t ws_size,
                              hipStream_t stream) {
  const float* x  = (const float*)d_in[0];
  const float* W  = (const float*)d_in[1];
  const float* bx = (const float*)d_in[2];
  const float* bh = (const float*)d_in[3];

  const size_t IMG = (size_t)DD * HH * 2;   // 1 MB each
  if (ws_size < 2 * IMG + 64) return;

  unsigned short* WTC = (unsigned short*)d_ws;
  unsigned short* WX2 = (unsigned short*)((char*)d_ws + IMG);
  double* S = (double*)((char*)d_ws + 2 * IMG);

  hipMemsetAsync(S, 0, 2 * sizeof(double), stream);

  RbmKeys K;
  for (int i = 0; i < 4; ++i) {
    uint32_t a, b;
    tf2x32_host(0u, 42u, 0u, (uint32_t)(2 * i), a, b);
    K.kh[i] = a ^ (b * 0x9E3779B9u);
    tf2x32_host(0u, 42u, 0u, (uint32_t)(2 * i + 1), a, b);
    K.kx[i] = a ^ (b * 0x9E3779B9u);
  }

  k_prep<<<(DD * HH) / 512, 512, 0, stream>>>(W, WTC, WX2);
  k_rbm<<<BB / 32, 512, 0, stream>>>(x, WTC, WX2, bx, bh, S, K);
  k_final<<<1, 64, 0, stream>>>(S, (float*)d_out);
}

// Round 7
// 416.735 us; speedup vs baseline: 1.2671x; 1.2671x over previous
//
#include <hip/hip_runtime.h>
#include <stdint.h>

// RBM CD-4, fused single kernel. 512 blocks x 32 rows (16 low rows bt16..bt16+15
// paired with bt16+8192..+15; pair shares one 32-bit hash: lo16/hi16).
// h-pass: C^T[j][b] = W^T X^T, K=4096, 64 chunks staged via global_load_lds into a
//   RING-3 LDS buffer, prefetch depth 2, counted s_waitcnt vmcnt(2) + RAW s_barrier
//   (r6 used __syncthreads, whose implicit vmcnt(0) defeated the counted wait).
// x-pass: K=128, barrier-free, direct WX2 loads (r6's reg-dbuf spilled: WRITE 150MB).
// RNG: lowbias32 counter hash; sample via fma(h,q,h) < 65536 (no rcp).
// ws: [WTC 1MB][WX2 1MB][S 2 doubles]

#define BB 16384
#define DD 4096
#define HH 128

typedef float f32x4 __attribute__((ext_vector_type(4)));
typedef short s16x8 __attribute__((ext_vector_type(8)));

struct RbmKeys { uint32_t kh[4]; uint32_t kx[4]; };

// host-only: threefry for key derivation
static void tf2x32_host(uint32_t k0, uint32_t k1, uint32_t x0, uint32_t x1,
                        uint32_t& o0, uint32_t& o1) {
  uint32_t ks2 = k0 ^ k1 ^ 0x1BD11BDAu;
  x0 += k0; x1 += k1;
#define TFR(r) { x0 += x1; x1 = (x1 << (r)) | (x1 >> (32 - (r))); x1 ^= x0; }
  TFR(13) TFR(15) TFR(26) TFR(6)
  x0 += k1; x1 += ks2 + 1u;
  TFR(17) TFR(29) TFR(16) TFR(24)
  x0 += ks2; x1 += k0 + 2u;
  TFR(13) TFR(15) TFR(26) TFR(6)
  x0 += k0; x1 += k1 + 3u;
  TFR(17) TFR(29) TFR(16) TFR(24)
  x0 += k1; x1 += ks2 + 4u;
  TFR(13) TFR(15) TFR(26) TFR(6)
  x0 += ks2; x1 += k0 + 5u;
#undef TFR
  o0 = x0; o1 = x1;
}

__device__ __forceinline__ uint32_t mix32(uint32_t x) {   // lowbias32
  x ^= x >> 16; x *= 0x21f0aaadu;
  x ^= x >> 15; x *= 0x735a2d97u;
  x ^= x >> 15;
  return x;
}

// sample: u16 < 65536*sigm(z)  <=>  fma(h, 2^(-z*log2e), h) < 65536
__device__ __forceinline__ bool samp16(uint32_t h16, float z) {
  float q = __builtin_amdgcn_exp2f(-1.442695041f * z);
  float hf = (float)h16;
  return fmaf(hf, q, hf) < 65536.0f;
}
__device__ __forceinline__ float softplusf(float z) {
  float e = __builtin_amdgcn_exp2f(-1.442695041f * fabsf(z));
  return fmaxf(z, 0.0f) + log1pf(e);
}

__device__ __forceinline__ void gload16(const void* g, void* l) {
  __builtin_amdgcn_global_load_lds(
      (const __attribute__((address_space(1))) uint32_t*)(uintptr_t)g,
      (__attribute__((address_space(3))) uint32_t*)(uintptr_t)l, 16, 0, 0);
}

// byte (8 bits) -> 8 packed bf16 {0,1}
__device__ __forceinline__ s16x8 expand8(uint32_t byte) {
  uint32_t n0 = byte & 0xFu, n1 = byte >> 4;
  union { s16x8 v; uint32_t u[4]; } r;
  r.u[0] = ((n0 * 0x40008001u) & 0x00010001u) * 0x3F80u;
  r.u[1] = (((n0 >> 2) * 0x40008001u) & 0x00010001u) * 0x3F80u;
  r.u[2] = ((n1 * 0x40008001u) & 0x00010001u) * 0x3F80u;
  r.u[3] = (((n1 >> 2) * 0x40008001u) & 0x00010001u) * 0x3F80u;
  return r.v;
}

// ---- W fp32 [D][H] -> WTC (h-image: 64-d chunks [128 j][64 d], XOR-swizzled)
//                    -> WX2 (x-image: [dt=d>>4][jg=j>>3][dl=d&15][je=j&7], 16B/lane)
__global__ __launch_bounds__(512) void k_prep(const float* __restrict__ W,
                                              unsigned short* __restrict__ WTC,
                                              unsigned short* __restrict__ WX2) {
  unsigned idx = blockIdx.x * 512u + threadIdx.x;   // over D*H
  uint32_t u = __float_as_uint(W[idx]);
  unsigned short r = (unsigned short)((u + 0x7FFFu + ((u >> 16) & 1u)) >> 16); // RTNE
  unsigned d = idx >> 7, j = idx & 127u;
  unsigned c = d >> 6, dloc = d & 63u;
  WTC[c * 8192u + j * 64u + (dloc ^ ((j & 7u) << 3))] = r;
  WX2[((d >> 4) * 16u + (j >> 3)) * 128u + (d & 15u) * 8u + (j & 7u)] = r;
}

__global__ __launch_bounds__(512, 4) void k_rbm(const float* __restrict__ x,
                                                const unsigned short* __restrict__ WTC,
                                                const unsigned short* __restrict__ WX2,
                                                const float* __restrict__ bx,
                                                const float* __restrict__ bh,
                                                double* __restrict__ S,
                                                RbmKeys K) {
  __shared__ unsigned short wt[3][8192];   // 48 KB ring-3 chunk buffer (h-pass)
  __shared__ uint32_t xbits[32 * 132];     // 16.9 KB: 32 rows x 128 words (+4 pad)
  __shared__ uint32_t hb[32 * 4];          // 512 B
  __shared__ double sred[8];

  const int t = threadIdx.x;
  const int l = t & 63;
  const int w = t >> 6;
  const int rs = l >> 4;
  const int l15 = l & 15;
  const unsigned bt16 = blockIdx.x * 16u;   // rows: lr<16 -> bt16+lr ; lr>=16 -> +8192

  const int wr = w >> 1, wc = w & 1;   // h-pass: j-quarter (32 j), row-half (16 rows)

  // hoist bh into registers
  float bhv[2][4];
#pragma unroll
  for (int rg = 0; rg < 2; ++rg)
#pragma unroll
    for (int reg = 0; reg < 4; ++reg)
      bhv[rg][reg] = bh[wr * 32 + rg * 16 + rs * 4 + reg];

  // ---------- P0: load x rows, pack bits, accumulate x.bx ----------
  {
    float vbx = 0.f;
#pragma unroll 1
    for (int q = 0; q < 4; ++q) {
      const int lr = w * 4 + q;
      const unsigned g = bt16 + (unsigned)(lr & 15) + (unsigned)((lr >> 4) << 13);
      const f32x4* xrow = (const f32x4*)(x + (size_t)g * DD);
#pragma unroll
      for (int it = 0; it < 16; ++it) {
        f32x4 v = xrow[it * 64 + l];
        f32x4 bv = *(const f32x4*)(bx + it * 256 + l * 4);
        vbx += v.x * bv.x + v.y * bv.y + v.z * bv.z + v.w * bv.w;
        uint32_t nib = (v.x != 0.f ? 1u : 0u) | (v.y != 0.f ? 2u : 0u) |
                       (v.z != 0.f ? 4u : 0u) | (v.w != 0.f ? 8u : 0u);
        uint32_t word = nib << (4 * (l & 7));
        word |= __shfl_xor(word, 1);
        word |= __shfl_xor(word, 2);
        word |= __shfl_xor(word, 4);
        if ((l & 7) == 0) xbits[lr * 132 + it * 8 + (l >> 3)] = word;
      }
    }
#pragma unroll
    for (int off = 32; off; off >>= 1) vbx += __shfl_xor(vbx, off);
    if (l == 0) sred[w] = (double)vbx;
    __syncthreads();
    if (t == 0) {
      double s = 0.0;
      for (int i = 0; i < 8; ++i) s += sred[i];
      atomicAdd(S + 0, s);
    }
  }

#pragma unroll 1
  for (int step = 0; step < 5; ++step) {
    // ================= h-pass: K=4096 over 64 WTC chunks, ring-3, depth-2 =================
    f32x4 acc[2];
    acc[0] = (f32x4){0.f, 0.f, 0.f, 0.f};
    acc[1] = (f32x4){0.f, 0.f, 0.f, 0.f};

    // drain stragglers (P0 / x-pass loads / atomics) so counted waits are exact
    asm volatile("s_waitcnt vmcnt(0)" ::: "memory");
    {
      const char* src = (const char*)WTC + (t << 4);
      char* dst = (char*)&wt[0][0] + (t << 4);
      gload16(src, dst);                       // chunk 0 -> slot 0
      gload16(src + 8192, dst + 8192);
      gload16(src + 16384, dst + 16384);       // chunk 1 -> slot 1
      gload16(src + 24576, dst + 24576);
    }
    int rd = 0, wsl = 2;
#pragma unroll 1
    for (int c = 0; c < 64; ++c) {
      // wait for THIS chunk's loads only (keep deeper prefetch in flight);
      // lgkmcnt(0) makes this wave's xbits/hb ds_writes visible before the barrier.
      if (c < 63) asm volatile("s_waitcnt vmcnt(2) lgkmcnt(0)" ::: "memory");
      else        asm volatile("s_waitcnt vmcnt(0) lgkmcnt(0)" ::: "memory");
      __builtin_amdgcn_s_barrier();            // raw: no implicit vmcnt(0) drain
      asm volatile("" ::: "memory");
      if (c < 62) {
        const char* src = (const char*)WTC + ((size_t)(c + 2) << 14) + (t << 4);
        char* dst = (char*)&wt[0][0] + (wsl << 14) + (t << 4);
        gload16(src, dst);
        gload16(src + 8192, dst + 8192);
      }
      const int xrow = (wc * 16 + l15) * 132 + c * 2;
      uint32_t w0 = xbits[xrow];
      uint32_t w1 = xbits[xrow + 1];
      const unsigned short* wb = wt[rd];
#pragma unroll
      for (int kk = 0; kk < 2; ++kk) {
        s16x8 bf = expand8(((kk ? w1 : w0) >> (8 * rs)) & 0xffu);
#pragma unroll
        for (int rg = 0; rg < 2; ++rg) {
          const int j = wr * 32 + rg * 16 + l15;
          s16x8 af = *(const s16x8*)&wb[j * 64 + ((kk * 32 + rs * 8) ^ ((l15 & 7) << 3))];
          acc[rg] = __builtin_amdgcn_mfma_f32_16x16x32_bf16(af, bf, acc[rg], 0, 0, 0);
        }
      }
      rd = (rd == 2) ? 0 : rd + 1;
      wsl = (wsl == 2) ? 0 : wsl + 1;
    }

    // ---------- h epilogue: sample h (steps 0-3) / energy (steps 0,4) ----------
    if (step < 4) {
      const uint32_t key = K.kh[step];
      const unsigned glow = bt16 + (unsigned)l15;
      uint32_t mask = 0;
      float loc = 0.f;
#pragma unroll
      for (int rg = 0; rg < 2; ++rg)
#pragma unroll
        for (int reg = 0; reg < 4; ++reg) {
          const int jj = wr * 32 + rg * 16 + rs * 4 + reg;
          float z = acc[rg][reg] + bhv[rg][reg];
          if (step == 0) loc += softplusf(z);
          uint32_t h32 = mix32((glow * 128u + (unsigned)jj) ^ key);
          uint32_t h16 = wc ? (h32 >> 16) : (h32 & 0xffffu);
          mask |= (samp16(h16, z) ? 1u : 0u) << (rg * 16 + rs * 4 + reg);
        }
      mask |= __shfl_xor(mask, 16);
      mask |= __shfl_xor(mask, 32);
      if (rs == 0) hb[(wc * 16 + l15) * 4 + wr] = mask;
      if (step == 0) {
#pragma unroll
        for (int off = 32; off; off >>= 1) loc += __shfl_xor(loc, off);
        if (l == 0) sred[w] = (double)loc;
      }
      __syncthreads();   // hb (and sred) visible; also fences wt readers before next prologue
      if (step == 0 && t == 0) {
        double s = 0.0;
        for (int i = 0; i < 8; ++i) s += sred[i];
        atomicAdd(S + 0, s);
      }
    } else {
      float loc = 0.f;
#pragma unroll
      for (int rg = 0; rg < 2; ++rg)
#pragma unroll
        for (int reg = 0; reg < 4; ++reg)
          loc += softplusf(acc[rg][reg] + bhv[rg][reg]);
#pragma unroll
      for (int off = 32; off; off >>= 1) loc += __shfl_xor(loc, off);
      if (l == 0) sred[w] = (double)loc;
      __syncthreads();
      if (t == 0) {
        double s = 0.0;
        for (int i = 0; i < 8; ++i) s += sred[i];
        atomicAdd(S + 1, s);
      }
    }

    // ================= x-pass: K=128, barrier-free, direct WX2 loads =================
    if (step < 4) {
      const uint32_t key = K.kx[step];
      s16x8 bfr[4][2];   // h B-fragments, hoisted for whole pass
#pragma unroll
      for (int ch = 0; ch < 4; ++ch)
#pragma unroll
        for (int cg = 0; cg < 2; ++cg) {
          uint32_t hw = hb[(cg * 16 + l15) * 4 + ch];
          bfr[ch][cg] = expand8((hw >> (8 * rs)) & 0xffu);
        }
      float vbx1 = 0.f;
      const unsigned mrow = (bt16 + (unsigned)l15) * 4096u;
#pragma unroll 1
      for (int dsub = 0; dsub < 16; ++dsub) {
        const int dbase = w * 512 + dsub * 32;
        s16x8 af[2][4];
#pragma unroll
        for (int rg = 0; rg < 2; ++rg) {
          const unsigned dt = (unsigned)(w * 32 + dsub * 2 + rg);
#pragma unroll
          for (int ch = 0; ch < 4; ++ch)
            af[rg][ch] = *(const s16x8*)(WX2 + dt * 2048u +
                                         (unsigned)(ch * 4 + rs) * 128u + (unsigned)l15 * 8u);
        }
        f32x4 acc2[2][2];
        acc2[0][0] = (f32x4){0.f,0.f,0.f,0.f}; acc2[0][1] = (f32x4){0.f,0.f,0.f,0.f};
        acc2[1][0] = (f32x4){0.f,0.f,0.f,0.f}; acc2[1][1] = (f32x4){0.f,0.f,0.f,0.f};
#pragma unroll
        for (int ch = 0; ch < 4; ++ch)
#pragma unroll
          for (int rg = 0; rg < 2; ++rg)
#pragma unroll
            for (int cg = 0; cg < 2; ++cg)
              acc2[rg][cg] = __builtin_amdgcn_mfma_f32_16x16x32_bf16(af[rg][ch], bfr[ch][cg],
                                                                     acc2[rg][cg], 0, 0, 0);
        uint32_t ml = 0, mh = 0;
#pragma unroll
        for (int rg = 0; rg < 2; ++rg) {
          f32x4 bx4 = *(const f32x4*)(bx + dbase + rg * 16 + rs * 4);
#pragma unroll
          for (int reg = 0; reg < 4; ++reg) {
            const int pos = rg * 16 + rs * 4 + reg;
            const unsigned d = (unsigned)(dbase + pos);
            uint32_t h32 = mix32((mrow + d) ^ key);
            float zl = acc2[rg][0][reg] + bx4[reg];
            float zh = acc2[rg][1][reg] + bx4[reg];
            bool sl = samp16(h32 & 0xffffu, zl);
            bool sh = samp16(h32 >> 16, zh);
            ml |= (sl ? 1u : 0u) << pos;
            mh |= (sh ? 1u : 0u) << pos;
            if (step == 3) vbx1 += bx4[reg] * ((sl ? 1.f : 0.f) + (sh ? 1.f : 0.f));
          }
        }
        unsigned long long mm = (unsigned long long)ml | ((unsigned long long)mh << 32);
        mm |= __shfl_xor(mm, 16);
        mm |= __shfl_xor(mm, 32);
        if (rs == 0) {
          xbits[l15 * 132 + w * 16 + dsub] = (uint32_t)mm;
          xbits[(16 + l15) * 132 + w * 16 + dsub] = (uint32_t)(mm >> 32);
        }
      }
      if (step == 3) {
#pragma unroll
        for (int off = 32; off; off >>= 1) vbx1 += __shfl_xor(vbx1, off);
        if (l == 0) sred[w] = (double)vbx1;
        __syncthreads();
        if (t == 0) {
          double s = 0.0;
          for (int i = 0; i < 8; ++i) s += sred[i];
          atomicAdd(S + 1, s);
        }
      }
      // no trailing barrier: next h-pass's c=0 lgkmcnt(0)+barrier orders xbits
    }
  }
}

__global__ void k_final(const double* __restrict__ S, float* __restrict__ out) {
  if (threadIdx.x == 0 && blockIdx.x == 0)
    out[0] = (float)((S[1] - S[0]) / (double)BB);   // mean F(x) - mean F(x_rec)
}

extern "C" void kernel_launch(void* const* d_in, const int* in_sizes, int n_in,
                              void* d_out, int out_size, void* d_ws, size_t ws_size,
                              hipStream_t stream) {
  const float* x  = (const float*)d_in[0];
  const float* W  = (const float*)d_in[1];
  const float* bx = (const float*)d_in[2];
  const float* bh = (const float*)d_in[3];

  const size_t IMG = (size_t)DD * HH * 2;   // 1 MB each
  if (ws_size < 2 * IMG + 64) return;

  unsigned short* WTC = (unsigned short*)d_ws;
  unsigned short* WX2 = (unsigned short*)((char*)d_ws + IMG);
  double* S = (double*)((char*)d_ws + 2 * IMG);

  hipMemsetAsync(S, 0, 2 * sizeof(double), stream);

  RbmKeys K;
  for (int i = 0; i < 4; ++i) {
    uint32_t a, b;
    tf2x32_host(0u, 42u, 0u, (uint32_t)(2 * i), a, b);
    K.kh[i] = a ^ (b * 0x9E3779B9u);
    tf2x32_host(0u, 42u, 0u, (uint32_t)(2 * i + 1), a, b);
    K.kx[i] = a ^ (b * 0x9E3779B9u);
  }

  k_prep<<<(DD * HH) / 512, 512, 0, stream>>>(W, WTC, WX2);
  k_rbm<<<BB / 32, 512, 0, stream>>>(x, WTC, WX2, bx, bh, S, K);
  k_final<<<1, 64, 0, stream>>>(S, (float*)d_out);
}

// Round 8
// 392.950 us; speedup vs baseline: 1.3438x; 1.0605x over previous
//
#include <hip/hip_runtime.h>
#include <stdint.h>

// RBM CD-4, fused single kernel. 512 blocks x 32 rows (16 low rows bt16..bt16+15
// paired with bt16+8192..+15; pair shares one 32-bit hash: lo16/hi16).
// R8: W is L2-resident (1 MB bf16) -> NO LDS staging at all. Both passes read
// W fragments directly from fragment-ordered global images (WH for h-pass,
// WX2 for x-pass). Zero in-loop barriers; ~12 barriers per block total.
// RNG: lowbias32 counter hash; sample via fma(h,q,h) < 65536.
// ws: [WH 1MB][WX2 1MB][S 2 doubles]

#define BB 16384
#define DD 4096
#define HH 128

typedef float f32x4 __attribute__((ext_vector_type(4)));
typedef short s16x8 __attribute__((ext_vector_type(8)));

struct RbmKeys { uint32_t kh[4]; uint32_t kx[4]; };

// host-only: threefry for key derivation
static void tf2x32_host(uint32_t k0, uint32_t k1, uint32_t x0, uint32_t x1,
                        uint32_t& o0, uint32_t& o1) {
  uint32_t ks2 = k0 ^ k1 ^ 0x1BD11BDAu;
  x0 += k0; x1 += k1;
#define TFR(r) { x0 += x1; x1 = (x1 << (r)) | (x1 >> (32 - (r))); x1 ^= x0; }
  TFR(13) TFR(15) TFR(26) TFR(6)
  x0 += k1; x1 += ks2 + 1u;
  TFR(17) TFR(29) TFR(16) TFR(24)
  x0 += ks2; x1 += k0 + 2u;
  TFR(13) TFR(15) TFR(26) TFR(6)
  x0 += k0; x1 += k1 + 3u;
  TFR(17) TFR(29) TFR(16) TFR(24)
  x0 += k1; x1 += ks2 + 4u;
  TFR(13) TFR(15) TFR(26) TFR(6)
  x0 += ks2; x1 += k0 + 5u;
#undef TFR
  o0 = x0; o1 = x1;
}

__device__ __forceinline__ uint32_t mix32(uint32_t x) {   // lowbias32
  x ^= x >> 16; x *= 0x21f0aaadu;
  x ^= x >> 15; x *= 0x735a2d97u;
  x ^= x >> 15;
  return x;
}

// sample: u16 < 65536*sigm(z)  <=>  fma(h, 2^(-z*log2e), h) < 65536
__device__ __forceinline__ bool samp16(uint32_t h16, float z) {
  float q = __builtin_amdgcn_exp2f(-1.442695041f * z);
  float hf = (float)h16;
  return fmaf(hf, q, hf) < 65536.0f;
}
__device__ __forceinline__ float softplusf(float z) {
  float e = __builtin_amdgcn_exp2f(-1.442695041f * fabsf(z));
  return fmaxf(z, 0.0f) + log1pf(e);
}

// byte (8 bits) -> 8 packed bf16 {0,1}
__device__ __forceinline__ s16x8 expand8(uint32_t byte) {
  uint32_t n0 = byte & 0xFu, n1 = byte >> 4;
  union { s16x8 v; uint32_t u[4]; } r;
  r.u[0] = ((n0 * 0x40008001u) & 0x00010001u) * 0x3F80u;
  r.u[1] = (((n0 >> 2) * 0x40008001u) & 0x00010001u) * 0x3F80u;
  r.u[2] = ((n1 * 0x40008001u) & 0x00010001u) * 0x3F80u;
  r.u[3] = (((n1 >> 2) * 0x40008001u) & 0x00010001u) * 0x3F80u;
  return r.v;
}

// ---- W fp32 [D][H] -> WH  (h-image:  granule g=(d>>3)*128+j holds W[d&~7 .. +8][j] as bf16)
//                    -> WX2 (x-image: [dt=d>>4][jg=j>>3][dl=d&15][je=j&7], 16B/lane) ----
__global__ __launch_bounds__(512) void k_prep(const float* __restrict__ W,
                                              unsigned short* __restrict__ WH,
                                              unsigned short* __restrict__ WX2) {
  unsigned idx = blockIdx.x * 512u + threadIdx.x;   // over D*H
  uint32_t u = __float_as_uint(W[idx]);
  unsigned short r = (unsigned short)((u + 0x7FFFu + ((u >> 16) & 1u)) >> 16); // RTNE
  unsigned d = idx >> 7, j = idx & 127u;
  WH[((d >> 3) * 128u + j) * 8u + (d & 7u)] = r;
  WX2[((d >> 4) * 16u + (j >> 3)) * 128u + (d & 15u) * 8u + (j & 7u)] = r;
}

__global__ __launch_bounds__(512, 4) void k_rbm(const float* __restrict__ x,
                                                const unsigned short* __restrict__ WH,
                                                const unsigned short* __restrict__ WX2,
                                                const float* __restrict__ bx,
                                                const float* __restrict__ bh,
                                                double* __restrict__ S,
                                                RbmKeys K) {
  __shared__ uint32_t xbits[32 * 132];     // 16.9 KB: 32 rows x 128 words (+4 pad)
  __shared__ uint32_t hb[32 * 4];          // 512 B
  __shared__ double sred[8];

  const int t = threadIdx.x;
  const int l = t & 63;
  const int w = t >> 6;
  const int rs = l >> 4;
  const int l15 = l & 15;
  const unsigned bt16 = blockIdx.x * 16u;   // rows: lr<16 -> bt16+lr ; lr>=16 -> +8192

  const int wr = w >> 1, wc = w & 1;   // h-pass: j-quarter (32 j), row-half (16 rows)

  // hoist bh into registers
  float bhv[2][4];
#pragma unroll
  for (int rg = 0; rg < 2; ++rg)
#pragma unroll
    for (int reg = 0; reg < 4; ++reg)
      bhv[rg][reg] = bh[wr * 32 + rg * 16 + rs * 4 + reg];

  // ---------- P0: load x rows, pack bits, accumulate x.bx ----------
  {
    float vbx = 0.f;
#pragma unroll 1
    for (int q = 0; q < 4; ++q) {
      const int lr = w * 4 + q;
      const unsigned g = bt16 + (unsigned)(lr & 15) + (unsigned)((lr >> 4) << 13);
      const f32x4* xrow = (const f32x4*)(x + (size_t)g * DD);
#pragma unroll
      for (int it = 0; it < 16; ++it) {
        f32x4 v = xrow[it * 64 + l];
        f32x4 bv = *(const f32x4*)(bx + it * 256 + l * 4);
        vbx += v.x * bv.x + v.y * bv.y + v.z * bv.z + v.w * bv.w;
        uint32_t nib = (v.x != 0.f ? 1u : 0u) | (v.y != 0.f ? 2u : 0u) |
                       (v.z != 0.f ? 4u : 0u) | (v.w != 0.f ? 8u : 0u);
        uint32_t word = nib << (4 * (l & 7));
        word |= __shfl_xor(word, 1);
        word |= __shfl_xor(word, 2);
        word |= __shfl_xor(word, 4);
        if ((l & 7) == 0) xbits[lr * 132 + it * 8 + (l >> 3)] = word;
      }
    }
#pragma unroll
    for (int off = 32; off; off >>= 1) vbx += __shfl_xor(vbx, off);
    if (l == 0) sred[w] = (double)vbx;
    __syncthreads();
    if (t == 0) {
      double s = 0.0;
      for (int i = 0; i < 8; ++i) s += sred[i];
      atomicAdd(S + 0, s);
    }
  }

#pragma unroll 1
  for (int step = 0; step < 5; ++step) {
    // ========== h-pass: C^T[j][b] = W^T X^T, K=4096, direct WH loads, no barriers ==========
    __syncthreads();   // previous x-pass xbits writes visible
    f32x4 acc[2];
    acc[0] = (f32x4){0.f, 0.f, 0.f, 0.f};
    acc[1] = (f32x4){0.f, 0.f, 0.f, 0.f};
#pragma unroll 2
    for (int c = 0; c < 64; ++c) {
      const int xrow = (wc * 16 + l15) * 132 + c * 2;
      uint32_t w0 = xbits[xrow];
      uint32_t w1 = xbits[xrow + 1];
#pragma unroll
      for (int kk = 0; kk < 2; ++kk) {
        s16x8 bf = expand8(((kk ? w1 : w0) >> (8 * rs)) & 0xffu);
#pragma unroll
        for (int rg = 0; rg < 2; ++rg) {
          const s16x8 af = *(const s16x8*)(WH +
              ((unsigned)(c * 8 + kk * 4 + rs) * 128u +
               (unsigned)(wr * 32 + rg * 16 + l15)) * 8u);
          acc[rg] = __builtin_amdgcn_mfma_f32_16x16x32_bf16(af, bf, acc[rg], 0, 0, 0);
        }
      }
    }

    // ---------- h epilogue: sample h (steps 0-3) / energy (steps 0,4) ----------
    if (step < 4) {
      const uint32_t key = K.kh[step];
      const unsigned glow = bt16 + (unsigned)l15;
      uint32_t mask = 0;
      float loc = 0.f;
#pragma unroll
      for (int rg = 0; rg < 2; ++rg)
#pragma unroll
        for (int reg = 0; reg < 4; ++reg) {
          const int jj = wr * 32 + rg * 16 + rs * 4 + reg;
          float z = acc[rg][reg] + bhv[rg][reg];
          if (step == 0) loc += softplusf(z);
          uint32_t h32 = mix32((glow * 128u + (unsigned)jj) ^ key);
          uint32_t h16 = wc ? (h32 >> 16) : (h32 & 0xffffu);
          mask |= (samp16(h16, z) ? 1u : 0u) << (rg * 16 + rs * 4 + reg);
        }
      mask |= __shfl_xor(mask, 16);
      mask |= __shfl_xor(mask, 32);
      if (rs == 0) hb[(wc * 16 + l15) * 4 + wr] = mask;
      if (step == 0) {
#pragma unroll
        for (int off = 32; off; off >>= 1) loc += __shfl_xor(loc, off);
        if (l == 0) sred[w] = (double)loc;
      }
      __syncthreads();   // hb (and sred) visible
      if (step == 0 && t == 0) {
        double s = 0.0;
        for (int i = 0; i < 8; ++i) s += sred[i];
        atomicAdd(S + 0, s);
      }
    } else {
      float loc = 0.f;
#pragma unroll
      for (int rg = 0; rg < 2; ++rg)
#pragma unroll
        for (int reg = 0; reg < 4; ++reg)
          loc += softplusf(acc[rg][reg] + bhv[rg][reg]);
#pragma unroll
      for (int off = 32; off; off >>= 1) loc += __shfl_xor(loc, off);
      if (l == 0) sred[w] = (double)loc;
      __syncthreads();
      if (t == 0) {
        double s = 0.0;
        for (int i = 0; i < 8; ++i) s += sred[i];
        atomicAdd(S + 1, s);
      }
    }

    // ================= x-pass: K=128, barrier-free, direct WX2 loads =================
    if (step < 4) {
      const uint32_t key = K.kx[step];
      s16x8 bfr[4][2];   // h B-fragments, hoisted for whole pass
#pragma unroll
      for (int ch = 0; ch < 4; ++ch)
#pragma unroll
        for (int cg = 0; cg < 2; ++cg) {
          uint32_t hw = hb[(cg * 16 + l15) * 4 + ch];
          bfr[ch][cg] = expand8((hw >> (8 * rs)) & 0xffu);
        }
      float vbx1 = 0.f;
      const unsigned mrow = (bt16 + (unsigned)l15) * 4096u;
#pragma unroll 1
      for (int dsub = 0; dsub < 16; ++dsub) {
        const int dbase = w * 512 + dsub * 32;
        s16x8 af[2][4];
#pragma unroll
        for (int rg = 0; rg < 2; ++rg) {
          const unsigned dt = (unsigned)(w * 32 + dsub * 2 + rg);
#pragma unroll
          for (int ch = 0; ch < 4; ++ch)
            af[rg][ch] = *(const s16x8*)(WX2 + dt * 2048u +
                                         (unsigned)(ch * 4 + rs) * 128u + (unsigned)l15 * 8u);
        }
        f32x4 acc2[2][2];
        acc2[0][0] = (f32x4){0.f,0.f,0.f,0.f}; acc2[0][1] = (f32x4){0.f,0.f,0.f,0.f};
        acc2[1][0] = (f32x4){0.f,0.f,0.f,0.f}; acc2[1][1] = (f32x4){0.f,0.f,0.f,0.f};
#pragma unroll
        for (int ch = 0; ch < 4; ++ch)
#pragma unroll
          for (int rg = 0; rg < 2; ++rg)
#pragma unroll
            for (int cg = 0; cg < 2; ++cg)
              acc2[rg][cg] = __builtin_amdgcn_mfma_f32_16x16x32_bf16(af[rg][ch], bfr[ch][cg],
                                                                     acc2[rg][cg], 0, 0, 0);
        uint32_t ml = 0, mh = 0;
#pragma unroll
        for (int rg = 0; rg < 2; ++rg) {
          f32x4 bx4 = *(const f32x4*)(bx + dbase + rg * 16 + rs * 4);
#pragma unroll
          for (int reg = 0; reg < 4; ++reg) {
            const int pos = rg * 16 + rs * 4 + reg;
            const unsigned d = (unsigned)(dbase + pos);
            uint32_t h32 = mix32((mrow + d) ^ key);
            float zl = acc2[rg][0][reg] + bx4[reg];
            float zh = acc2[rg][1][reg] + bx4[reg];
            bool sl = samp16(h32 & 0xffffu, zl);
            bool sh = samp16(h32 >> 16, zh);
            ml |= (sl ? 1u : 0u) << pos;
            mh |= (sh ? 1u : 0u) << pos;
            if (step == 3) vbx1 += bx4[reg] * ((sl ? 1.f : 0.f) + (sh ? 1.f : 0.f));
          }
        }
        unsigned long long mm = (unsigned long long)ml | ((unsigned long long)mh << 32);
        mm |= __shfl_xor(mm, 16);
        mm |= __shfl_xor(mm, 32);
        if (rs == 0) {
          xbits[l15 * 132 + w * 16 + dsub] = (uint32_t)mm;
          xbits[(16 + l15) * 132 + w * 16 + dsub] = (uint32_t)(mm >> 32);
        }
      }
      if (step == 3) {
#pragma unroll
        for (int off = 32; off; off >>= 1) vbx1 += __shfl_xor(vbx1, off);
        if (l == 0) sred[w] = (double)vbx1;
        __syncthreads();
        if (t == 0) {
          double s = 0.0;
          for (int i = 0; i < 8; ++i) s += sred[i];
          atomicAdd(S + 1, s);
        }
      }
      // next h-pass begins with __syncthreads(), ordering these xbits writes
    }
  }
}

__global__ void k_final(const double* __restrict__ S, float* __restrict__ out) {
  if (threadIdx.x == 0 && blockIdx.x == 0)
    out[0] = (float)((S[1] - S[0]) / (double)BB);   // mean F(x) - mean F(x_rec)
}

extern "C" void kernel_launch(void* const* d_in, const int* in_sizes, int n_in,
                              void* d_out, int out_size, void* d_ws, size_t ws_size,
                              hipStream_t stream) {
  const float* x  = (const float*)d_in[0];
  const float* W  = (const float*)d_in[1];
  const float* bx = (const float*)d_in[2];
  const float* bh = (const float*)d_in[3];

  const size_t IMG = (size_t)DD * HH * 2;   // 1 MB each
  if (ws_size < 2 * IMG + 64) return;

  unsigned short* WH  = (unsigned short*)d_ws;
  unsigned short* WX2 = (unsigned short*)((char*)d_ws + IMG);
  double* S = (double*)((char*)d_ws + 2 * IMG);

  hipMemsetAsync(S, 0, 2 * sizeof(double), stream);

  RbmKeys K;
  for (int i = 0; i < 4; ++i) {
    uint32_t a, b;
    tf2x32_host(0u, 42u, 0u, (uint32_t)(2 * i), a, b);
    K.kh[i] = a ^ (b * 0x9E3779B9u);
    tf2x32_host(0u, 42u, 0u, (uint32_t)(2 * i + 1), a, b);
    K.kx[i] = a ^ (b * 0x9E3779B9u);
  }

  k_prep<<<(DD * HH) / 512, 512, 0, stream>>>(W, WH, WX2);
  k_rbm<<<BB / 32, 512, 0, stream>>>(x, WH, WX2, bx, bh, S, K);
  k_final<<<1, 64, 0, stream>>>(S, (float*)d_out);
}